// Round 1
// baseline (11129.847 us; speedup 1.0000x reference)
//
#include <hip/hip_runtime.h>

// Problem dims
#define BB 128
#define LL 64
#define DD 256
#define HH 512
#define NEGC (-1e9f)

// Persistent grid: 256 blocks x 512 threads, one block per CU.
#define NBLK 256
#define NTHR 512

// ws offsets (floats) — same layout as previous version; smask region now hosts
// the grid-barrier counters (smask moved into per-block registers).
#define OFF_DENSE   0            // B*L*D   = 2,097,152
#define OFF_ENCOUT  2097152      // B*L*H   = 4,194,304
#define OFF_ENCKEYS 6291456      // B*L*512 = 4,194,304
#define OFF_PTRKEYS 10485760     // B*L*256 = 2,097,152
#define OFF_X       12582912     // B*768   [ctx(512)|dec_in(256)]
#define OFF_HB0     12681216     // B*H
#define OFF_HB1     12746752     // B*H
#define OFF_H0      12812288     // B*H
#define OFF_Q       12877824     // B*512
#define OFF_PQ      12943360     // B*256
#define OFF_WQT     12976128     // 512*512 (s2s_Wq transposed)
#define OFF_MT      13238272     // 256*512 (W_out^T @ ptr_Wq, [a][h])
#define OFF_BQ      13369344     // 256
#define OFF_BAR     13369600     // grid barrier: cnt @ +0, gen @ +64 uints

__device__ __forceinline__ float fast_tanh(float x) {
  float e = __expf(2.0f * x);
  return 1.0f - 2.0f / (e + 1.0f);   // safe at +-inf
}
__device__ __forceinline__ float sigmoidf_(float x) {
  return 1.0f / (1.0f + __expf(-x));
}
__device__ __forceinline__ float wsum(float v) {
#pragma unroll
  for (int o = 32; o > 0; o >>= 1) v += __shfl_xor(v, o);
  return v;
}

#define D4(acc) fmaf(xv.x, w.x, fmaf(xv.y, w.y, fmaf(xv.z, w.z, fmaf(xv.w, w.w, acc))))

struct MegaArgs {
  const float* inputs; const int* lengths; const int* targets;
  const float* W_in; const float* b_in;
  const float* enc_Wi; const float* enc_Wh; const float* enc_bi; const float* enc_bh;
  const float* dec_Wi; const float* dec_Wh; const float* dec_bi; const float* dec_bh;
  const float* s2s_Wq; const float* s2s_Wk; const float* s2s_v;
  const float* W_out; const float* b_out;
  const float* ptr_Wq; const float* ptr_Wk; const float* ptr_v;
  float* ws; float* logits; float* preds;
};

// Grid barrier. __syncthreads() first: compiler emits s_waitcnt vmcnt(0) per wave,
// so ALL waves' global stores have reached L2 before tid0 arrives. The ACQ_REL
// fetch_add (agent scope) releases (L2 writeback -> L3-visible cross-XCD); the
// ACQUIRE load on exit invalidates stale cache lines. Monotonic generation
// counter; cnt always returns to 0, so state is replay-safe.
__device__ __forceinline__ void gridbar(unsigned* cnt, unsigned* gen) {
  __syncthreads();
  if (threadIdx.x == 0) {
    unsigned g = __hip_atomic_load(gen, __ATOMIC_RELAXED, __HIP_MEMORY_SCOPE_AGENT);
    unsigned v = __hip_atomic_fetch_add(cnt, 1u, __ATOMIC_ACQ_REL, __HIP_MEMORY_SCOPE_AGENT);
    if (v == (unsigned)(NBLK - 1)) {
      __hip_atomic_store(cnt, 0u, __ATOMIC_RELAXED, __HIP_MEMORY_SCOPE_AGENT);
      __hip_atomic_store(gen, g + 1u, __ATOMIC_RELEASE, __HIP_MEMORY_SCOPE_AGENT);
    } else {
      while (__hip_atomic_load(gen, __ATOMIC_RELAXED, __HIP_MEMORY_SCOPE_AGENT) == g)
        __builtin_amdgcn_s_sleep(2);
      (void)__hip_atomic_load(gen, __ATOMIC_ACQUIRE, __HIP_MEMORY_SCOPE_AGENT);
    }
  }
  __syncthreads();
}

struct SMem {
  union {
    struct { float xs[16 * 772];  float part[4 * 16 * 8 * 8]; } e;    // encoder gates
    struct { float xs[16 * 1284]; float part[4 * 16 * 8 * 8]; } p2;   // dec gates (98.5 KB max)
    struct { float hs[16 * 516];  float part[4 * 16 * 24];    } p3;   // q/pq GEMM
    struct { float s[32 * 256]; } pk;                                  // ptr_keys
    struct { float s[16 * 512]; } ek;                                  // enc_keys
    struct { float sq[512]; float sv[512]; float sl[64]; float wl[64]; } a1;
  };
};

__global__ __launch_bounds__(NTHR) void mega(MegaArgs a) {
  const int blk = blockIdx.x;
  const int tid = threadIdx.x;
  float* ws = a.ws;
  float* dense    = ws + OFF_DENSE;
  float* enc_out  = ws + OFF_ENCOUT;
  float* enc_keys = ws + OFF_ENCKEYS;
  float* ptr_keys = ws + OFF_PTRKEYS;
  float* xbuf     = ws + OFF_X;
  float* hb0      = ws + OFF_HB0;
  float* hb1      = ws + OFF_HB1;
  float* h0       = ws + OFF_H0;
  float* qbuf     = ws + OFF_Q;
  float* pqbuf    = ws + OFF_PQ;
  float* Wqt      = ws + OFF_WQT;
  float* Mt       = ws + OFF_MT;
  float* bqv      = ws + OFF_BQ;
  unsigned* cnt   = (unsigned*)(ws + OFF_BAR);
  unsigned* gen   = (unsigned*)(ws + OFF_BAR) + 64;

  __shared__ SMem sm;

  // per-block pointer step_mask for batch b == blk (blocks 0..127 own one batch each)
  unsigned long long alive = ~0ull;

  // ---------------- S1: dense, Wqt, Mt, bq, zero hb0 ----------------
  for (int idx = blk * NTHR + tid; idx < BB * LL * DD; idx += NBLK * NTHR) {
    int bl = idx >> 8, d = idx & 255;
    dense[idx] = fmaf(a.inputs[bl * 2], a.W_in[d * 2],
                 fmaf(a.inputs[bl * 2 + 1], a.W_in[d * 2 + 1], a.b_in[d]));
  }
  for (int idx = blk * NTHR + tid; idx < 512 * 512; idx += NBLK * NTHR) {
    int h = idx >> 9, q = idx & 511;
    Wqt[q * 512 + h] = a.s2s_Wq[idx];
  }
  for (int idx = blk * NTHR + tid; idx < BB * HH; idx += NBLK * NTHR) hb0[idx] = 0.f;
  {
    float acc = 0.f;
    for (int d = 0; d < 256; ++d)
      acc = fmaf(a.W_out[d * 512 + tid], a.ptr_Wq[d * 256 + blk], acc);
    Mt[blk * 512 + tid] = acc;
  }
  if (blk == 0 && tid < 256) {
    float acc = 0.f;
    for (int d = 0; d < 256; ++d) acc = fmaf(a.b_out[d], a.ptr_Wq[d * 256 + tid], acc);
    bqv[tid] = acc;
  }
  gridbar(cnt, gen);

  // ---------------- PK: ptr_keys = dense @ ptr_Wk (32 rows/block) ----------------
  {
    const int r0 = blk * 32;
    for (int idx = tid; idx < 32 * 256; idx += NTHR) sm.pk.s[idx] = dense[r0 * 256 + idx];
    __syncthreads();
    const int col = tid & 255, rg = tid >> 8;
    float acc[16];
#pragma unroll
    for (int ri = 0; ri < 16; ++ri) acc[ri] = 0.f;
    const float* srow = sm.pk.s + rg * 16 * 256;
    for (int d = 0; d < 256; ++d) {
      float w = a.ptr_Wk[d * 256 + col];
#pragma unroll
      for (int ri = 0; ri < 16; ++ri) acc[ri] = fmaf(srow[ri * 256 + d], w, acc[ri]);
    }
#pragma unroll
    for (int ri = 0; ri < 16; ++ri)
      ptr_keys[(r0 + rg * 16 + ri) * 256 + col] = acc[ri];
  }
  gridbar(cnt, gen);

  // ---------------- encoder: 64 GRU steps, b-tile 16 x u-tile 16 ----------------
#pragma unroll 1
  for (int t = 0; t < 64; ++t) {
    const int b0 = (blk >> 5) * 16, u0 = (blk & 31) * 16;
    const float* hin = (t & 1) ? hb1 : hb0;
    float* hout = (t & 1) ? hb0 : hb1;
    for (int idx = tid; idx < 16 * 768; idx += NTHR) {
      int bl = idx / 768, k = idx - bl * 768;
      sm.e.xs[bl * 772 + k] = (k < 512) ? hin[(b0 + bl) * 512 + k]
                                        : dense[((b0 + bl) * 64 + t) * 256 + (k - 512)];
    }
    __syncthreads();
    {
      const int b_l = tid & 15, og = (tid >> 4) & 7, kp = tid >> 7;
      const int ua = u0 + og * 2;
      float ar0 = 0, az0 = 0, ain0 = 0, ahn0 = 0, ar1 = 0, az1 = 0, ain1 = 0, ahn1 = 0;
      const float* xr = sm.e.xs + b_l * 772;
      const int k0 = kp * 192, k1 = k0 + 192;
      const int kA = (k1 < 512) ? k1 : 512;
      for (int k = k0; k < kA; k += 4) {
        float4 xv = *(const float4*)(xr + k);
        float4 w;
        w = *(const float4*)(a.enc_Wh + (ua) * 512 + k);        ar0  = D4(ar0);
        w = *(const float4*)(a.enc_Wh + (512 + ua) * 512 + k);  az0  = D4(az0);
        w = *(const float4*)(a.enc_Wh + (1024 + ua) * 512 + k); ahn0 = D4(ahn0);
        w = *(const float4*)(a.enc_Wh + (ua + 1) * 512 + k);    ar1  = D4(ar1);
        w = *(const float4*)(a.enc_Wh + (513 + ua) * 512 + k);  az1  = D4(az1);
        w = *(const float4*)(a.enc_Wh + (1025 + ua) * 512 + k); ahn1 = D4(ahn1);
      }
      const int kB = (k0 > 512) ? k0 : 512;
      for (int k = kB; k < k1; k += 4) {
        float4 xv = *(const float4*)(xr + k);
        float4 w;
        w = *(const float4*)(a.enc_Wi + (ua) * 256 + k - 512);        ar0  = D4(ar0);
        w = *(const float4*)(a.enc_Wi + (512 + ua) * 256 + k - 512);  az0  = D4(az0);
        w = *(const float4*)(a.enc_Wi + (1024 + ua) * 256 + k - 512); ain0 = D4(ain0);
        w = *(const float4*)(a.enc_Wi + (ua + 1) * 256 + k - 512);    ar1  = D4(ar1);
        w = *(const float4*)(a.enc_Wi + (513 + ua) * 256 + k - 512);  az1  = D4(az1);
        w = *(const float4*)(a.enc_Wi + (1025 + ua) * 256 + k - 512); ain1 = D4(ain1);
      }
      float* pp = sm.e.part + ((kp * 16 + b_l) * 8 + og) * 8;
      pp[0] = ar0; pp[1] = az0; pp[2] = ain0; pp[3] = ahn0;
      pp[4] = ar1; pp[5] = az1; pp[6] = ain1; pp[7] = ahn1;
    }
    __syncthreads();
    if (tid < 256) {
      const int b_l = tid & 15, u_l = tid >> 4;
      const int og = u_l >> 1, uu = u_l & 1;
      float ar = 0, az = 0, ain = 0, ahn = 0;
#pragma unroll
      for (int kp = 0; kp < 4; ++kp) {
        const float* p = sm.e.part + ((kp * 16 + b_l) * 8 + og) * 8 + uu * 4;
        ar += p[0]; az += p[1]; ain += p[2]; ahn += p[3];
      }
      const int u = u0 + u_l, b = b0 + b_l;
      float r = sigmoidf_(ar + a.enc_bi[u] + a.enc_bh[u]);
      float z = sigmoidf_(az + a.enc_bi[512 + u] + a.enc_bh[512 + u]);
      float n = fast_tanh(ain + a.enc_bi[1024 + u] + r * (ahn + a.enc_bh[1024 + u]));
      float hp = sm.e.xs[b_l * 772 + u];
      float hn = (1.f - z) * n + z * hp;
      hout[b * 512 + u] = hn;
      int lenb = a.lengths[b];
      enc_out[(b * 64 + t) * 512 + u] = (t < lenb) ? hn : 0.f;
      if (t == lenb - 1) h0[b * 512 + u] = hn;
    }
    gridbar(cnt, gen);
  }

  // ---- phase lambdas ----
  // A0: [q(512)|pq(256)] = h @ [Wqt|Mt]^T ; b-tile 16 x o-tile 24
  auto phaseA0 = [&](const float* hsrc) {
    const int b0 = (blk >> 5) * 16, o0 = (blk & 31) * 24;
    for (int idx = tid; idx < 16 * 512; idx += NTHR) {
      int bl = idx >> 9, k = idx & 511;
      sm.p3.hs[bl * 516 + k] = hsrc[(b0 + bl) * 512 + k];
    }
    __syncthreads();
    {
      const int b_l = tid & 15, og = (tid >> 4) & 7, kp = tid >> 7;
      const int oa = o0 + og * 3;
      const float* w0 = (oa     < 512) ? (Wqt + oa * 512)       : (Mt + (oa - 512) * 512);
      const float* w1 = (oa + 1 < 512) ? (Wqt + (oa + 1) * 512) : (Mt + (oa - 511) * 512);
      const float* w2 = (oa + 2 < 512) ? (Wqt + (oa + 2) * 512) : (Mt + (oa - 510) * 512);
      float c0 = 0, c1 = 0, c2 = 0;
      const float* xr = sm.p3.hs + b_l * 516;
      const int k0 = kp * 128;
      for (int k = k0; k < k0 + 128; k += 4) {
        float4 xv = *(const float4*)(xr + k);
        float4 w;
        w = *(const float4*)(w0 + k); c0 = D4(c0);
        w = *(const float4*)(w1 + k); c1 = D4(c1);
        w = *(const float4*)(w2 + k); c2 = D4(c2);
      }
      float* pp = sm.p3.part + (kp * 16 + b_l) * 24 + og * 3;
      pp[0] = c0; pp[1] = c1; pp[2] = c2;
    }
    __syncthreads();
    if (tid < 384) {
      const int b_l = tid & 15, o_l = tid >> 4;
      float s = 0.f;
#pragma unroll
      for (int kp = 0; kp < 4; ++kp) s += sm.p3.part[(kp * 16 + b_l) * 24 + o_l];
      const int b = b0 + b_l, o = o0 + o_l;
      if (o < 512) qbuf[b * 512 + o] = s;
      else pqbuf[b * 256 + (o - 512)] = s + bqv[o - 512];
    }
  };

  // A1: pointer output (j=step-1) + s2s attention (step); block b = blk < 128
  auto phaseA1 = [&](int step) {
    if (blk >= BB) return;
    const int b = blk;
    const int wv = tid >> 6, ln = tid & 63;
    const int lenb = a.lengths[b];
    if (step > 0) {
      const int j = step - 1;
      if (tid < 256) { sm.a1.sq[tid] = pqbuf[b * 256 + tid]; sm.a1.sv[tid] = a.ptr_v[tid]; }
      __syncthreads();
#pragma unroll
      for (int li = 0; li < 8; ++li) {
        int l = wv * 8 + li;
        float acc = 0.f;
#pragma unroll
        for (int c = 0; c < 4; ++c) {
          int q = c * 64 + ln;
          acc = fmaf(fast_tanh(sm.a1.sq[q] + ptr_keys[(b * 64 + l) * 256 + q]), sm.a1.sv[q], acc);
        }
        acc = wsum(acc);
        if (ln == 0) sm.a1.sl[l] = acc;
      }
      __syncthreads();
      if (tid < 64) {
        int l = tid;
        bool pm = (j < lenb) && (l < lenb) && ((alive >> l) & 1ull);
        float v = pm ? sm.a1.sl[l] : NEGC;
        a.logits[(b * 64 + j) * 64 + l] = v;
        float bv = v; int bidx = l;
#pragma unroll
        for (int off = 32; off > 0; off >>= 1) {
          float ov = __shfl_xor(bv, off);
          int oi = __shfl_xor(bidx, off);
          if (ov > bv || (ov == bv && oi < bidx)) { bv = ov; bidx = oi; }
        }
        if (l == 0) a.preds[b * 64 + j] = (float)bidx;
      }
      alive &= ~(1ull << (unsigned)a.targets[b * 64 + j]);  // uniform update, after reads above
      __syncthreads();
    }
    if (step < 64) {
      const int i = step;
      sm.a1.sq[tid] = qbuf[b * 512 + tid];
      sm.a1.sv[tid] = a.s2s_v[tid];
      __syncthreads();
#pragma unroll
      for (int li = 0; li < 8; ++li) {
        int l = wv * 8 + li;
        float acc = 0.f;
#pragma unroll
        for (int c = 0; c < 8; ++c) {
          int q = c * 64 + ln;
          acc = fmaf(fast_tanh(sm.a1.sq[q] + enc_keys[(b * 64 + l) * 512 + q]), sm.a1.sv[q], acc);
        }
        acc = wsum(acc);
        if (ln == 0) sm.a1.sl[l] = ((i < lenb) && (l < lenb)) ? acc : NEGC;
      }
      __syncthreads();
      if (tid < 64) {
        float v = sm.a1.sl[tid];
        float m = v;
#pragma unroll
        for (int off = 32; off > 0; off >>= 1) m = fmaxf(m, __shfl_xor(m, off));
        float e = __expf(v - m);
        float s = e;
#pragma unroll
        for (int off = 32; off > 0; off >>= 1) s += __shfl_xor(s, off);
        sm.a1.wl[tid] = e / s;
      }
      __syncthreads();
      {
        float c = 0.f;
#pragma unroll 8
        for (int l = 0; l < 64; ++l) c = fmaf(sm.a1.wl[l], enc_out[(b * 64 + l) * 512 + tid], c);
        xbuf[b * 768 + tid] = c;
      }
      if (tid < 256) {
        int di = (i == 0) ? 0 : a.targets[b * 64 + i - 1];
        xbuf[b * 768 + 512 + tid] = dense[(b * 64 + di) * 256 + tid];
      }
    }
  };

  // ---------------- EK: enc_keys = enc_out @ s2s_Wk (2 tiles of 16 rows) + A0(step0) ----------------
#pragma unroll 1
  for (int rep = 0; rep < 2; ++rep) {
    const int r0 = (blk * 2 + rep) * 16;
    for (int idx = tid; idx < 16 * 512; idx += NTHR) sm.ek.s[idx] = enc_out[r0 * 512 + idx];
    __syncthreads();
    float acc[16];
#pragma unroll
    for (int ri = 0; ri < 16; ++ri) acc[ri] = 0.f;
    for (int h = 0; h < 512; ++h) {
      float w = a.s2s_Wk[h * 512 + tid];
#pragma unroll
      for (int ri = 0; ri < 16; ++ri) acc[ri] = fmaf(sm.ek.s[ri * 512 + h], w, acc[ri]);
    }
#pragma unroll
    for (int ri = 0; ri < 16; ++ri) enc_keys[(r0 + ri) * 512 + tid] = acc[ri];
    __syncthreads();
  }
  phaseA0(h0);   // q/pq for decoder step 0
  gridbar(cnt, gen);

  // ---------------- decoder: 64 steps x {A1, B(gates), A0(next q/pq)} ----------------
#pragma unroll 1
  for (int i = 0; i < 64; ++i) {
    phaseA1(i);
    gridbar(cnt, gen);
    {  // B: gates GEMM + GRU pointwise; b-tile 16 x u-tile 16
      const int b0 = (blk >> 5) * 16, u0 = (blk & 31) * 16;
      const float* hin = (i == 0) ? h0 : ((i & 1) ? hb1 : hb0);
      float* hout = (i & 1) ? hb0 : hb1;
      for (int idx = tid; idx < 16 * 1280; idx += NTHR) {
        int bl = idx / 1280, k = idx - bl * 1280;
        sm.p2.xs[bl * 1284 + k] = (k < 768) ? xbuf[(b0 + bl) * 768 + k]
                                            : hin[(b0 + bl) * 512 + (k - 768)];
      }
      __syncthreads();
      {
        const int b_l = tid & 15, og = (tid >> 4) & 7, kp = tid >> 7;
        const int ua = u0 + og * 2;
        float ar0 = 0, az0 = 0, ain0 = 0, ahn0 = 0, ar1 = 0, az1 = 0, ain1 = 0, ahn1 = 0;
        const float* xr = sm.p2.xs + b_l * 1284;
        const int k0 = kp * 320, k1 = k0 + 320;
        const int kA = (k1 < 768) ? k1 : 768;
        for (int k = k0; k < kA; k += 4) {
          float4 xv = *(const float4*)(xr + k);
          float4 w;
          w = *(const float4*)(a.dec_Wi + (ua) * 768 + k);        ar0  = D4(ar0);
          w = *(const float4*)(a.dec_Wi + (512 + ua) * 768 + k);  az0  = D4(az0);
          w = *(const float4*)(a.dec_Wi + (1024 + ua) * 768 + k); ain0 = D4(ain0);
          w = *(const float4*)(a.dec_Wi + (ua + 1) * 768 + k);    ar1  = D4(ar1);
          w = *(const float4*)(a.dec_Wi + (513 + ua) * 768 + k);  az1  = D4(az1);
          w = *(const float4*)(a.dec_Wi + (1025 + ua) * 768 + k); ain1 = D4(ain1);
        }
        const int kB = (k0 > 768) ? k0 : 768;
        for (int k = kB; k < k1; k += 4) {
          float4 xv = *(const float4*)(xr + k);
          float4 w;
          w = *(const float4*)(a.dec_Wh + (ua) * 512 + k - 768);        ar0  = D4(ar0);
          w = *(const float4*)(a.dec_Wh + (512 + ua) * 512 + k - 768);  az0  = D4(az0);
          w = *(const float4*)(a.dec_Wh + (1024 + ua) * 512 + k - 768); ahn0 = D4(ahn0);
          w = *(const float4*)(a.dec_Wh + (ua + 1) * 512 + k - 768);    ar1  = D4(ar1);
          w = *(const float4*)(a.dec_Wh + (513 + ua) * 512 + k - 768);  az1  = D4(az1);
          w = *(const float4*)(a.dec_Wh + (1025 + ua) * 512 + k - 768); ahn1 = D4(ahn1);
        }
        float* pp = sm.p2.part + ((kp * 16 + b_l) * 8 + og) * 8;
        pp[0] = ar0; pp[1] = az0; pp[2] = ain0; pp[3] = ahn0;
        pp[4] = ar1; pp[5] = az1; pp[6] = ain1; pp[7] = ahn1;
      }
      __syncthreads();
      if (tid < 256) {
        const int b_l = tid & 15, u_l = tid >> 4;
        const int og = u_l >> 1, uu = u_l & 1;
        float ar = 0, az = 0, ain = 0, ahn = 0;
#pragma unroll
        for (int kp = 0; kp < 4; ++kp) {
          const float* p = sm.p2.part + ((kp * 16 + b_l) * 8 + og) * 8 + uu * 4;
          ar += p[0]; az += p[1]; ain += p[2]; ahn += p[3];
        }
        const int u = u0 + u_l, b = b0 + b_l;
        float r = sigmoidf_(ar + a.dec_bi[u] + a.dec_bh[u]);
        float z = sigmoidf_(az + a.dec_bi[512 + u] + a.dec_bh[512 + u]);
        float n = fast_tanh(ain + a.dec_bi[1024 + u] + r * (ahn + a.dec_bh[1024 + u]));
        float hp = sm.p2.xs[b_l * 1284 + 768 + u];
        hout[b * 512 + u] = (1.f - z) * n + z * hp;
      }
    }
    gridbar(cnt, gen);
    phaseA0((i & 1) ? hb0 : hb1);   // q/pq for step i+1 (and final pointer pass)
    gridbar(cnt, gen);
  }
  phaseA1(64);   // emit pointer outputs for j=63
}

extern "C" void kernel_launch(void* const* d_in, const int* in_sizes, int n_in,
                              void* d_out, int out_size, void* d_ws, size_t ws_size,
                              hipStream_t stream) {
  (void)in_sizes; (void)n_in; (void)out_size; (void)ws_size;
  MegaArgs ma;
  ma.inputs  = (const float*)d_in[0];
  ma.lengths = (const int*)d_in[1];
  ma.targets = (const int*)d_in[2];
  ma.W_in    = (const float*)d_in[3];
  ma.b_in    = (const float*)d_in[4];
  ma.enc_Wi  = (const float*)d_in[5];
  ma.enc_Wh  = (const float*)d_in[6];
  ma.enc_bi  = (const float*)d_in[7];
  ma.enc_bh  = (const float*)d_in[8];
  ma.dec_Wi  = (const float*)d_in[9];
  ma.dec_Wh  = (const float*)d_in[10];
  ma.dec_bi  = (const float*)d_in[11];
  ma.dec_bh  = (const float*)d_in[12];
  ma.s2s_Wq  = (const float*)d_in[13];
  ma.s2s_Wk  = (const float*)d_in[14];
  ma.s2s_v   = (const float*)d_in[15];
  ma.W_out   = (const float*)d_in[16];
  ma.b_out   = (const float*)d_in[17];
  ma.ptr_Wq  = (const float*)d_in[18];
  ma.ptr_Wk  = (const float*)d_in[19];
  ma.ptr_v   = (const float*)d_in[20];
  ma.ws     = (float*)d_ws;
  ma.logits = (float*)d_out;
  ma.preds  = (float*)d_out + BB * LL * LL;

  // init barrier counters (graph-capturable; kernel is also self-consistent on replay)
  hipMemsetAsync((float*)d_ws + OFF_BAR, 0, 512, stream);

  void* kp[] = { &ma };
  hipLaunchCooperativeKernel(reinterpret_cast<const void*>(&mega),
                             dim3(NBLK), dim3(NTHR), kp, 0, stream);
}

// Round 2
// 9821.056 us; speedup vs baseline: 1.1333x; 1.1333x over previous
//
#include <hip/hip_runtime.h>

// Problem dims
#define BB 128
#define LL 64
#define DD 256
#define HH 512
#define NEGC (-1e9f)

// Persistent grid: 256 blocks x 512 threads, one block per CU.
#define NBLK 256
#define NTHR 512

// ws offsets (floats)
#define OFF_DENSE   0            // B*L*D   = 2,097,152
#define OFF_ENCOUT  2097152      // B*L*H   = 4,194,304
#define OFF_ENCKEYS 6291456      // B*L*512 = 4,194,304
#define OFF_PTRKEYS 10485760     // B*L*256 = 2,097,152
#define OFF_X       12582912     // B*768   [ctx(512)|dec_in(256)]
#define OFF_HB0     12681216     // B*H
#define OFF_HB1     12746752     // B*H
#define OFF_H0      12812288     // B*H
#define OFF_Q       12877824     // B*512
#define OFF_PQ      12943360     // B*256
#define OFF_WQT     12976128     // 512*512 (s2s_Wq transposed)
#define OFF_MT      13238272     // 256*512 (W_out^T @ ptr_Wq, [a][h])
#define OFF_BQ      13369344     // 256
#define OFF_BAR     13369600     // tree barrier: leaf[i]@32i (i<16), root@512, gen@544 (uints)

__device__ __forceinline__ float fast_tanh(float x) {
  float e = __expf(2.0f * x);
  return 1.0f - 2.0f / (e + 1.0f);   // safe at +-inf
}
__device__ __forceinline__ float sigmoidf_(float x) {
  return 1.0f / (1.0f + __expf(-x));
}
__device__ __forceinline__ float wsum(float v) {
#pragma unroll
  for (int o = 32; o > 0; o >>= 1) v += __shfl_xor(v, o);
  return v;
}

// Coherent-point (sc0 sc1, cache-bypassing) accessors for cross-block data.
// Relaxed atomics at agent scope emit NO buffer_inv / buffer_wbl2 — L2 stays
// warm with weights. Only these small buffers pay the L3 round trip.
__device__ __forceinline__ float ldc(const float* p) {
  return __hip_atomic_load(p, __ATOMIC_RELAXED, __HIP_MEMORY_SCOPE_AGENT);
}
__device__ __forceinline__ void stc(float* p, float v) {
  __hip_atomic_store(p, v, __ATOMIC_RELAXED, __HIP_MEMORY_SCOPE_AGENT);
}

#define D4(acc) fmaf(xv.x, w.x, fmaf(xv.y, w.y, fmaf(xv.z, w.z, fmaf(xv.w, w.w, acc))))

struct MegaArgs {
  const float* inputs; const int* lengths; const int* targets;
  const float* W_in; const float* b_in;
  const float* enc_Wi; const float* enc_Wh; const float* enc_bi; const float* enc_bh;
  const float* dec_Wi; const float* dec_Wh; const float* dec_bi; const float* dec_bh;
  const float* s2s_Wq; const float* s2s_Wk; const float* s2s_v;
  const float* W_out; const float* b_out;
  const float* ptr_Wq; const float* ptr_Wk; const float* ptr_v;
  float* ws; float* logits; float* preds;
};

// Light grid barrier: relaxed tree (16 leaves x 16 + root), monotonic counters
// (mod-16 epochs -> replay-safe, no reset store). __syncthreads() drains
// vmcnt(0) per wave, so all sc1 stores reached the coherent point before tid0
// arrives. NO acquire/release -> NO L2 invalidation.
__device__ __forceinline__ void gridbar(unsigned* bar, int blk) {
  __syncthreads();
  if (threadIdx.x == 0) {
    unsigned* leaf = bar + ((blk >> 4) << 5);
    unsigned* root = bar + 512;
    unsigned* gen  = bar + 544;
    unsigned g = __hip_atomic_load(gen, __ATOMIC_RELAXED, __HIP_MEMORY_SCOPE_AGENT);
    unsigned v = __hip_atomic_fetch_add(leaf, 1u, __ATOMIC_RELAXED, __HIP_MEMORY_SCOPE_AGENT);
    if ((v & 15u) == 15u) {
      unsigned r = __hip_atomic_fetch_add(root, 1u, __ATOMIC_RELAXED, __HIP_MEMORY_SCOPE_AGENT);
      if ((r & 15u) == 15u)
        __hip_atomic_store(gen, g + 1u, __ATOMIC_RELAXED, __HIP_MEMORY_SCOPE_AGENT);
    }
    while (__hip_atomic_load(gen, __ATOMIC_RELAXED, __HIP_MEMORY_SCOPE_AGENT) == g)
      __builtin_amdgcn_s_sleep(16);
  }
  __syncthreads();
}

// Heavy barrier: full flush (wbl2) before, full invalidate after. Used exactly
// 3 times to hand off the big read-only buffers (dense/keys/enc_out/weights').
__device__ __forceinline__ void heavybar(unsigned* bar, int blk) {
  __syncthreads();
  if (threadIdx.x == 0) {
    __threadfence();   // release side: drain + writeback L2
    unsigned* leaf = bar + ((blk >> 4) << 5);
    unsigned* root = bar + 512;
    unsigned* gen  = bar + 544;
    unsigned g = __hip_atomic_load(gen, __ATOMIC_RELAXED, __HIP_MEMORY_SCOPE_AGENT);
    unsigned v = __hip_atomic_fetch_add(leaf, 1u, __ATOMIC_RELAXED, __HIP_MEMORY_SCOPE_AGENT);
    if ((v & 15u) == 15u) {
      unsigned r = __hip_atomic_fetch_add(root, 1u, __ATOMIC_RELAXED, __HIP_MEMORY_SCOPE_AGENT);
      if ((r & 15u) == 15u)
        __hip_atomic_store(gen, g + 1u, __ATOMIC_RELAXED, __HIP_MEMORY_SCOPE_AGENT);
    }
    while (__hip_atomic_load(gen, __ATOMIC_RELAXED, __HIP_MEMORY_SCOPE_AGENT) == g)
      __builtin_amdgcn_s_sleep(16);
    __threadfence();   // acquire side: invalidate stale cached lines
  }
  __syncthreads();
}

struct SMem {
  union {
    struct { float xs[16 * 772];  float part[4 * 16 * 8 * 8]; } e;    // encoder gates
    struct { float xs[16 * 1284]; float part[4 * 16 * 8 * 8]; } p2;   // dec gates (98.5 KB max)
    struct { float hs[16 * 516];  float part[4 * 16 * 24];    } p3;   // q/pq GEMM
    struct { float s[32 * 256]; } pk;                                  // ptr_keys
    struct { float s[16 * 512]; } ek;                                  // enc_keys
    struct { float sq[512]; float sv[512]; float sl[64]; float wl[64]; } a1;
  };
};

__global__ __launch_bounds__(NTHR) void mega(MegaArgs a) {
  const int blk = blockIdx.x;
  const int tid = threadIdx.x;
  float* ws = a.ws;
  float* dense    = ws + OFF_DENSE;
  float* enc_out  = ws + OFF_ENCOUT;
  float* enc_keys = ws + OFF_ENCKEYS;
  float* ptr_keys = ws + OFF_PTRKEYS;
  float* xbuf     = ws + OFF_X;
  float* hb0      = ws + OFF_HB0;
  float* hb1      = ws + OFF_HB1;
  float* h0       = ws + OFF_H0;
  float* qbuf     = ws + OFF_Q;
  float* pqbuf    = ws + OFF_PQ;
  float* Wqt      = ws + OFF_WQT;
  float* Mt       = ws + OFF_MT;
  float* bqv      = ws + OFF_BQ;
  unsigned* bar   = (unsigned*)(ws + OFF_BAR);

  __shared__ SMem sm;

  // per-block pointer step_mask for batch b == blk (blocks 0..127)
  unsigned long long alive = ~0ull;

  // ---------------- S1: dense, Wqt, Mt, bq, zero hb0 ----------------
  for (int idx = blk * NTHR + tid; idx < BB * LL * DD; idx += NBLK * NTHR) {
    int bl = idx >> 8, d = idx & 255;
    dense[idx] = fmaf(a.inputs[bl * 2], a.W_in[d * 2],
                 fmaf(a.inputs[bl * 2 + 1], a.W_in[d * 2 + 1], a.b_in[d]));
  }
  for (int idx = blk * NTHR + tid; idx < 512 * 512; idx += NBLK * NTHR) {
    int h = idx >> 9, q = idx & 511;
    Wqt[q * 512 + h] = a.s2s_Wq[idx];
  }
  for (int idx = blk * NTHR + tid; idx < BB * HH; idx += NBLK * NTHR) hb0[idx] = 0.f;
  {
    float acc = 0.f;
    for (int d = 0; d < 256; ++d)
      acc = fmaf(a.W_out[d * 512 + tid], a.ptr_Wq[d * 256 + blk], acc);
    Mt[blk * 512 + tid] = acc;
  }
  if (blk == 0 && tid < 256) {
    float acc = 0.f;
    for (int d = 0; d < 256; ++d) acc = fmaf(a.b_out[d], a.ptr_Wq[d * 256 + tid], acc);
    bqv[tid] = acc;
  }
  heavybar(bar, blk);

  // ---------------- PK: ptr_keys = dense @ ptr_Wk (32 rows/block) ----------------
  {
    const int r0 = blk * 32;
    for (int idx = tid; idx < 32 * 256; idx += NTHR) sm.pk.s[idx] = dense[r0 * 256 + idx];
    __syncthreads();
    const int col = tid & 255, rg = tid >> 8;
    float acc[16];
#pragma unroll
    for (int ri = 0; ri < 16; ++ri) acc[ri] = 0.f;
    const float* srow = sm.pk.s + rg * 16 * 256;
    for (int d = 0; d < 256; ++d) {
      float w = a.ptr_Wk[d * 256 + col];
#pragma unroll
      for (int ri = 0; ri < 16; ++ri) acc[ri] = fmaf(srow[ri * 256 + d], w, acc[ri]);
    }
#pragma unroll
    for (int ri = 0; ri < 16; ++ri)
      ptr_keys[(r0 + rg * 16 + ri) * 256 + col] = acc[ri];
  }
  heavybar(bar, blk);

  // ---------------- encoder: 64 GRU steps, b-tile 16 x u-tile 16 ----------------
#pragma unroll 1
  for (int t = 0; t < 64; ++t) {
    const int b0 = (blk >> 5) * 16, u0 = (blk & 31) * 16;
    const float* hin = (t & 1) ? hb1 : hb0;
    float* hout = (t & 1) ? hb0 : hb1;
    for (int idx = tid; idx < 16 * 768; idx += NTHR) {
      int bl = idx / 768, k = idx - bl * 768;
      sm.e.xs[bl * 772 + k] = (k < 512) ? ldc(&hin[(b0 + bl) * 512 + k])
                                        : dense[((b0 + bl) * 64 + t) * 256 + (k - 512)];
    }
    __syncthreads();
    {
      const int b_l = tid & 15, og = (tid >> 4) & 7, kp = tid >> 7;
      const int ua = u0 + og * 2;
      float ar0 = 0, az0 = 0, ain0 = 0, ahn0 = 0, ar1 = 0, az1 = 0, ain1 = 0, ahn1 = 0;
      const float* xr = sm.e.xs + b_l * 772;
      const int k0 = kp * 192, k1 = k0 + 192;
      const int kA = (k1 < 512) ? k1 : 512;
      for (int k = k0; k < kA; k += 4) {
        float4 xv = *(const float4*)(xr + k);
        float4 w;
        w = *(const float4*)(a.enc_Wh + (ua) * 512 + k);        ar0  = D4(ar0);
        w = *(const float4*)(a.enc_Wh + (512 + ua) * 512 + k);  az0  = D4(az0);
        w = *(const float4*)(a.enc_Wh + (1024 + ua) * 512 + k); ahn0 = D4(ahn0);
        w = *(const float4*)(a.enc_Wh + (ua + 1) * 512 + k);    ar1  = D4(ar1);
        w = *(const float4*)(a.enc_Wh + (513 + ua) * 512 + k);  az1  = D4(az1);
        w = *(const float4*)(a.enc_Wh + (1025 + ua) * 512 + k); ahn1 = D4(ahn1);
      }
      const int kB = (k0 > 512) ? k0 : 512;
      for (int k = kB; k < k1; k += 4) {
        float4 xv = *(const float4*)(xr + k);
        float4 w;
        w = *(const float4*)(a.enc_Wi + (ua) * 256 + k - 512);        ar0  = D4(ar0);
        w = *(const float4*)(a.enc_Wi + (512 + ua) * 256 + k - 512);  az0  = D4(az0);
        w = *(const float4*)(a.enc_Wi + (1024 + ua) * 256 + k - 512); ain0 = D4(ain0);
        w = *(const float4*)(a.enc_Wi + (ua + 1) * 256 + k - 512);    ar1  = D4(ar1);
        w = *(const float4*)(a.enc_Wi + (513 + ua) * 256 + k - 512);  az1  = D4(az1);
        w = *(const float4*)(a.enc_Wi + (1025 + ua) * 256 + k - 512); ain1 = D4(ain1);
      }
      float* pp = sm.e.part + ((kp * 16 + b_l) * 8 + og) * 8;
      pp[0] = ar0; pp[1] = az0; pp[2] = ain0; pp[3] = ahn0;
      pp[4] = ar1; pp[5] = az1; pp[6] = ain1; pp[7] = ahn1;
    }
    __syncthreads();
    if (tid < 256) {
      const int b_l = tid & 15, u_l = tid >> 4;
      const int og = u_l >> 1, uu = u_l & 1;
      float ar = 0, az = 0, ain = 0, ahn = 0;
#pragma unroll
      for (int kp = 0; kp < 4; ++kp) {
        const float* p = sm.e.part + ((kp * 16 + b_l) * 8 + og) * 8 + uu * 4;
        ar += p[0]; az += p[1]; ain += p[2]; ahn += p[3];
      }
      const int u = u0 + u_l, b = b0 + b_l;
      float r = sigmoidf_(ar + a.enc_bi[u] + a.enc_bh[u]);
      float z = sigmoidf_(az + a.enc_bi[512 + u] + a.enc_bh[512 + u]);
      float n = fast_tanh(ain + a.enc_bi[1024 + u] + r * (ahn + a.enc_bh[1024 + u]));
      float hp = sm.e.xs[b_l * 772 + u];
      float hn = (1.f - z) * n + z * hp;
      stc(&hout[b * 512 + u], hn);
      int lenb = a.lengths[b];
      enc_out[(b * 64 + t) * 512 + u] = (t < lenb) ? hn : 0.f;   // normal store; flushed below
      if (t == lenb - 1) h0[b * 512 + u] = hn;                    // normal store; flushed below
    }
    gridbar(bar, blk);
  }
  heavybar(bar, blk);   // flush enc_out/h0 for decoder-side cached readers

  // ---- phase lambdas ----
  // A0: [q(512)|pq(256)] = h @ [Wqt|Mt]^T ; b-tile 16 x o-tile 24
  auto phaseA0 = [&](const float* hsrc) {
    const int b0 = (blk >> 5) * 16, o0 = (blk & 31) * 24;
    for (int idx = tid; idx < 16 * 512; idx += NTHR) {
      int bl = idx >> 9, k = idx & 511;
      sm.p3.hs[bl * 516 + k] = ldc(&hsrc[(b0 + bl) * 512 + k]);
    }
    __syncthreads();
    {
      const int b_l = tid & 15, og = (tid >> 4) & 7, kp = tid >> 7;
      const int oa = o0 + og * 3;
      const float* w0 = (oa     < 512) ? (Wqt + oa * 512)       : (Mt + (oa - 512) * 512);
      const float* w1 = (oa + 1 < 512) ? (Wqt + (oa + 1) * 512) : (Mt + (oa - 511) * 512);
      const float* w2 = (oa + 2 < 512) ? (Wqt + (oa + 2) * 512) : (Mt + (oa - 510) * 512);
      float c0 = 0, c1 = 0, c2 = 0;
      const float* xr = sm.p3.hs + b_l * 516;
      const int k0 = kp * 128;
      for (int k = k0; k < k0 + 128; k += 4) {
        float4 xv = *(const float4*)(xr + k);
        float4 w;
        w = *(const float4*)(w0 + k); c0 = D4(c0);
        w = *(const float4*)(w1 + k); c1 = D4(c1);
        w = *(const float4*)(w2 + k); c2 = D4(c2);
      }
      float* pp = sm.p3.part + (kp * 16 + b_l) * 24 + og * 3;
      pp[0] = c0; pp[1] = c1; pp[2] = c2;
    }
    __syncthreads();
    if (tid < 384) {
      const int b_l = tid & 15, o_l = tid >> 4;
      float s = 0.f;
#pragma unroll
      for (int kp = 0; kp < 4; ++kp) s += sm.p3.part[(kp * 16 + b_l) * 24 + o_l];
      const int b = b0 + b_l, o = o0 + o_l;
      if (o < 512) stc(&qbuf[b * 512 + o], s);
      else stc(&pqbuf[b * 256 + (o - 512)], s + bqv[o - 512]);
    }
  };

  // A1: pointer output (j=step-1) + s2s attention (step); block b = blk < 128
  auto phaseA1 = [&](int step) {
    if (blk >= BB) return;
    const int b = blk;
    const int wv = tid >> 6, ln = tid & 63;
    const int lenb = a.lengths[b];
    if (step > 0) {
      const int j = step - 1;
      if (tid < 256) { sm.a1.sq[tid] = ldc(&pqbuf[b * 256 + tid]); sm.a1.sv[tid] = a.ptr_v[tid]; }
      __syncthreads();
#pragma unroll
      for (int li = 0; li < 8; ++li) {
        int l = wv * 8 + li;
        float acc = 0.f;
#pragma unroll
        for (int c = 0; c < 4; ++c) {
          int q = c * 64 + ln;
          acc = fmaf(fast_tanh(sm.a1.sq[q] + ptr_keys[(b * 64 + l) * 256 + q]), sm.a1.sv[q], acc);
        }
        acc = wsum(acc);
        if (ln == 0) sm.a1.sl[l] = acc;
      }
      __syncthreads();
      if (tid < 64) {
        int l = tid;
        bool pm = (j < lenb) && (l < lenb) && ((alive >> l) & 1ull);
        float v = pm ? sm.a1.sl[l] : NEGC;
        a.logits[(b * 64 + j) * 64 + l] = v;
        float bv = v; int bidx = l;
#pragma unroll
        for (int off = 32; off > 0; off >>= 1) {
          float ov = __shfl_xor(bv, off);
          int oi = __shfl_xor(bidx, off);
          if (ov > bv || (ov == bv && oi < bidx)) { bv = ov; bidx = oi; }
        }
        if (l == 0) a.preds[b * 64 + j] = (float)bidx;
      }
      alive &= ~(1ull << (unsigned)a.targets[b * 64 + j]);
      __syncthreads();
    }
    if (step < 64) {
      const int i = step;
      sm.a1.sq[tid] = ldc(&qbuf[b * 512 + tid]);
      sm.a1.sv[tid] = a.s2s_v[tid];
      __syncthreads();
#pragma unroll
      for (int li = 0; li < 8; ++li) {
        int l = wv * 8 + li;
        float acc = 0.f;
#pragma unroll
        for (int c = 0; c < 8; ++c) {
          int q = c * 64 + ln;
          acc = fmaf(fast_tanh(sm.a1.sq[q] + enc_keys[(b * 64 + l) * 512 + q]), sm.a1.sv[q], acc);
        }
        acc = wsum(acc);
        if (ln == 0) sm.a1.sl[l] = ((i < lenb) && (l < lenb)) ? acc : NEGC;
      }
      __syncthreads();
      if (tid < 64) {
        float v = sm.a1.sl[tid];
        float m = v;
#pragma unroll
        for (int off = 32; off > 0; off >>= 1) m = fmaxf(m, __shfl_xor(m, off));
        float e = __expf(v - m);
        float s = e;
#pragma unroll
        for (int off = 32; off > 0; off >>= 1) s += __shfl_xor(s, off);
        sm.a1.wl[tid] = e / s;
      }
      __syncthreads();
      {
        float c = 0.f;
#pragma unroll 8
        for (int l = 0; l < 64; ++l) c = fmaf(sm.a1.wl[l], enc_out[(b * 64 + l) * 512 + tid], c);
        stc(&xbuf[b * 768 + tid], c);
      }
      if (tid < 256) {
        int di = (i == 0) ? 0 : a.targets[b * 64 + i - 1];
        stc(&xbuf[b * 768 + 512 + tid], dense[(b * 64 + di) * 256 + tid]);
      }
    }
  };

  // ---------------- EK: enc_keys = enc_out @ s2s_Wk (2 tiles of 16 rows) + A0(step0) ----------------
#pragma unroll 1
  for (int rep = 0; rep < 2; ++rep) {
    const int r0 = (blk * 2 + rep) * 16;
    for (int idx = tid; idx < 16 * 512; idx += NTHR) sm.ek.s[idx] = enc_out[r0 * 512 + idx];
    __syncthreads();
    float acc[16];
#pragma unroll
    for (int ri = 0; ri < 16; ++ri) acc[ri] = 0.f;
    for (int h = 0; h < 512; ++h) {
      float w = a.s2s_Wk[h * 512 + tid];
#pragma unroll
      for (int ri = 0; ri < 16; ++ri) acc[ri] = fmaf(sm.ek.s[ri * 512 + h], w, acc[ri]);
    }
#pragma unroll
    for (int ri = 0; ri < 16; ++ri) enc_keys[(r0 + ri) * 512 + tid] = acc[ri];
    __syncthreads();
  }
  phaseA0(h0);   // q/pq for decoder step 0 (h0 is L3-fresh after heavybar)
  heavybar(bar, blk);   // flush enc_keys for A1's cached readers

  // ---------------- decoder: 64 steps x {A1, B(gates), A0(next q/pq)} ----------------
#pragma unroll 1
  for (int i = 0; i < 64; ++i) {
    phaseA1(i);
    gridbar(bar, blk);
    {  // B: gates GEMM + GRU pointwise; b-tile 16 x u-tile 16
      const int b0 = (blk >> 5) * 16, u0 = (blk & 31) * 16;
      const float* hin = (i == 0) ? h0 : ((i & 1) ? hb1 : hb0);
      float* hout = (i & 1) ? hb0 : hb1;
      for (int idx = tid; idx < 16 * 1280; idx += NTHR) {
        int bl = idx / 1280, k = idx - bl * 1280;
        sm.p2.xs[bl * 1284 + k] = (k < 768) ? ldc(&xbuf[(b0 + bl) * 768 + k])
                                            : ldc(&hin[(b0 + bl) * 512 + (k - 768)]);
      }
      __syncthreads();
      {
        const int b_l = tid & 15, og = (tid >> 4) & 7, kp = tid >> 7;
        const int ua = u0 + og * 2;
        float ar0 = 0, az0 = 0, ain0 = 0, ahn0 = 0, ar1 = 0, az1 = 0, ain1 = 0, ahn1 = 0;
        const float* xr = sm.p2.xs + b_l * 1284;
        const int k0 = kp * 320, k1 = k0 + 320;
        const int kA = (k1 < 768) ? k1 : 768;
        for (int k = k0; k < kA; k += 4) {
          float4 xv = *(const float4*)(xr + k);
          float4 w;
          w = *(const float4*)(a.dec_Wi + (ua) * 768 + k);        ar0  = D4(ar0);
          w = *(const float4*)(a.dec_Wi + (512 + ua) * 768 + k);  az0  = D4(az0);
          w = *(const float4*)(a.dec_Wi + (1024 + ua) * 768 + k); ain0 = D4(ain0);
          w = *(const float4*)(a.dec_Wi + (ua + 1) * 768 + k);    ar1  = D4(ar1);
          w = *(const float4*)(a.dec_Wi + (513 + ua) * 768 + k);  az1  = D4(az1);
          w = *(const float4*)(a.dec_Wi + (1025 + ua) * 768 + k); ain1 = D4(ain1);
        }
        const int kB = (k0 > 768) ? k0 : 768;
        for (int k = kB; k < k1; k += 4) {
          float4 xv = *(const float4*)(xr + k);
          float4 w;
          w = *(const float4*)(a.dec_Wh + (ua) * 512 + k - 768);        ar0  = D4(ar0);
          w = *(const float4*)(a.dec_Wh + (512 + ua) * 512 + k - 768);  az0  = D4(az0);
          w = *(const float4*)(a.dec_Wh + (1024 + ua) * 512 + k - 768); ahn0 = D4(ahn0);
          w = *(const float4*)(a.dec_Wh + (ua + 1) * 512 + k - 768);    ar1  = D4(ar1);
          w = *(const float4*)(a.dec_Wh + (513 + ua) * 512 + k - 768);  az1  = D4(az1);
          w = *(const float4*)(a.dec_Wh + (1025 + ua) * 512 + k - 768); ahn1 = D4(ahn1);
        }
        float* pp = sm.p2.part + ((kp * 16 + b_l) * 8 + og) * 8;
        pp[0] = ar0; pp[1] = az0; pp[2] = ain0; pp[3] = ahn0;
        pp[4] = ar1; pp[5] = az1; pp[6] = ain1; pp[7] = ahn1;
      }
      __syncthreads();
      if (tid < 256) {
        const int b_l = tid & 15, u_l = tid >> 4;
        const int og = u_l >> 1, uu = u_l & 1;
        float ar = 0, az = 0, ain = 0, ahn = 0;
#pragma unroll
        for (int kp = 0; kp < 4; ++kp) {
          const float* p = sm.p2.part + ((kp * 16 + b_l) * 8 + og) * 8 + uu * 4;
          ar += p[0]; az += p[1]; ain += p[2]; ahn += p[3];
        }
        const int u = u0 + u_l, b = b0 + b_l;
        float r = sigmoidf_(ar + a.dec_bi[u] + a.dec_bh[u]);
        float z = sigmoidf_(az + a.dec_bi[512 + u] + a.dec_bh[512 + u]);
        float n = fast_tanh(ain + a.dec_bi[1024 + u] + r * (ahn + a.dec_bh[1024 + u]));
        float hp = sm.p2.xs[b_l * 1284 + 768 + u];
        stc(&hout[b * 512 + u], (1.f - z) * n + z * hp);
      }
    }
    gridbar(bar, blk);
    phaseA0((i & 1) ? hb0 : hb1);   // q/pq for step i+1 (and final pointer pass)
    gridbar(bar, blk);
  }
  phaseA1(64);   // emit pointer outputs for j=63
}

extern "C" void kernel_launch(void* const* d_in, const int* in_sizes, int n_in,
                              void* d_out, int out_size, void* d_ws, size_t ws_size,
                              hipStream_t stream) {
  (void)in_sizes; (void)n_in; (void)out_size; (void)ws_size;
  MegaArgs ma;
  ma.inputs  = (const float*)d_in[0];
  ma.lengths = (const int*)d_in[1];
  ma.targets = (const int*)d_in[2];
  ma.W_in    = (const float*)d_in[3];
  ma.b_in    = (const float*)d_in[4];
  ma.enc_Wi  = (const float*)d_in[5];
  ma.enc_Wh  = (const float*)d_in[6];
  ma.enc_bi  = (const float*)d_in[7];
  ma.enc_bh  = (const float*)d_in[8];
  ma.dec_Wi  = (const float*)d_in[9];
  ma.dec_Wh  = (const float*)d_in[10];
  ma.dec_bi  = (const float*)d_in[11];
  ma.dec_bh  = (const float*)d_in[12];
  ma.s2s_Wq  = (const float*)d_in[13];
  ma.s2s_Wk  = (const float*)d_in[14];
  ma.s2s_v   = (const float*)d_in[15];
  ma.W_out   = (const float*)d_in[16];
  ma.b_out   = (const float*)d_in[17];
  ma.ptr_Wq  = (const float*)d_in[18];
  ma.ptr_Wk  = (const float*)d_in[19];
  ma.ptr_v   = (const float*)d_in[20];
  ma.ws     = (float*)d_ws;
  ma.logits = (float*)d_out;
  ma.preds  = (float*)d_out + BB * LL * LL;

  // init barrier region (first launch: ws is garbage). Monotonic mod-16 epochs
  // keep it self-consistent across graph replays even without re-zeroing.
  hipMemsetAsync((float*)d_ws + OFF_BAR, 0, 4096, stream);

  void* kp[] = { &ma };
  hipLaunchCooperativeKernel(reinterpret_cast<const void*>(&mega),
                             dim3(NBLK), dim3(NTHR), kp, 0, stream);
}